// Round 6
// baseline (215.043 us; speedup 1.0000x reference)
//
#include <hip/hip_runtime.h>
#include <hip/hip_bf16.h>
#include <cstdint>

#define QLEN   1024
#define KLEN   2048
#define DMODEL 2048
#define BATCH  4
#define FLEN   (KLEN - QLEN + 1)   // 1025

typedef __bf16 bf16x8 __attribute__((ext_vector_type(8)));
typedef __bf16 bf16x4 __attribute__((ext_vector_type(4)));
typedef float  f32x4  __attribute__((ext_vector_type(4)));

// Static device scratch.
__device__ __bf16 g_ft[(size_t)QLEN * KLEN];           // FT, scale baked, bf16 (4 MB)
__device__ __bf16 g_yt[(size_t)BATCH * DMODEL * KLEN]; // y^T = (x+p)^T per batch (33.5 MB)

typedef __attribute__((address_space(1))) void gvoid;
typedef __attribute__((address_space(3))) void svoid;

__device__ __forceinline__ void async_load16(const void* g, void* lds) {
  gvoid* gp = (gvoid*)(uintptr_t)g;
  svoid* sp = (svoid*)(uint32_t)(uintptr_t)lds;   // flat LDS addr low 32 bits == LDS offset
  __builtin_amdgcn_global_load_lds(gp, sp, 16, 0, 0);
}

// ---------------- FT generation ----------------
// FT[l,m] = cos(2*pi*((l*(m-l)) % 1025)/1025) / sqrt(1025*2048) inside band l<=m<=l+1024.
__global__ void gen_ft_kernel() {
  const int u  = blockIdx.x * 256 + threadIdx.x;  // over QLEN*KLEN/8
  const int l  = u >> 8;                          // KLEN/8 = 256 chunks per row
  const int m0 = (u & 255) * 8;
  const int j0 = m0 - l;
  bf16x8 o = {};
  if (j0 + 7 >= 0 && j0 < FLEN) {
    const float w     = 6.283185307179586f / (float)FLEN;
    const float scale = 1.0f / sqrtf((float)FLEN * (float)KLEN);
#pragma unroll
    for (int i = 0; i < 8; ++i) {
      const int j = j0 + i;
      float v = 0.0f;
      if (j >= 0 && j < FLEN) {
        const int r = (l * j) % FLEN;             // exact: l*j < 2^20, magic-mul mod
        v = cosf((float)r * w) * scale;
      }
      o[i] = (__bf16)v;
    }
  }
  *(bf16x8*)(g_ft + (size_t)u * 8) = o;
}

// ---------------- y^T generation (add + cast + transpose) ----------------
// yt[b][d][m] = bf16(x[b][m][d] + addf*p[b][m][d])
//
// Wave-autonomous, ZERO barriers (round-5 structure, round-6 bug fixes):
//  - global_load_lds LDS base must be WAVE-UNIFORM (m104): base xb+s*256;
//    HW places lane i at base+i*16B, which lands exactly as LDS[r][d_local]
//    with r = s*16 + (lane>>2), d_local = (lane&3)*4+e.
//  - vmcnt retires IN ORDER (m135): to guarantee unit j's 4 loads done, wait
//    vmcnt <= (#ops issued after them): j=0 -> 4 (no store yet!), j in 1..6
//    -> 5 (store(j-1) + next unit's 4), j=7 -> 1 (store(6) only).
// Each wave owns a private 8 KB double-buffered LDS region and pipelines 8
// units (32m x 16d); prefetched loads are never drained by a barrier.
__global__ __launch_bounds__(256) void gen_yt_kernel(const float* __restrict__ x,
                                                     const float* __restrict__ p,
                                                     const int* __restrict__ addp) {
  // [wave][buf][x=0/p=1][32 rows * 16 floats]
  __shared__ __align__(16) float lds[4][2][2][512];   // 32 KB
  const int t    = threadIdx.x;
  const int lane = t & 63;
  const int wave = t >> 6;
  const float addf = (*addp) ? 1.0f : 0.0f;

  // Wave -> strip mapping: W in [0,4096); 8 units of (32m x 16d) along d.
  const int W    = blockIdx.x * 4 + wave;         // grid 1024 blocks
  const int b    = W >> 10;                       // 1024 waves per batch
  const int rem  = W & 1023;
  const int mi   = rem >> 4;                      // 64 m-strips
  const int m0   = mi * 32;
  const int dw   = (rem & 15) * 128;              // wave's d base (8 units * 16)
  const size_t base = (size_t)b * KLEN * DMODEL;

  const int r_ld = lane >> 2;                     // sweep row 0..15
  const int q_ld = lane & 3;                      // 16B chunk in row
  const int d_l  = lane >> 2;                     // consume: local d 0..15
  const int mc   = lane & 3;                      // consume: m-chunk 0..3

  // Issue one unit's 4 async loads (2 sweeps x {x,p}) into buffer bb.
  auto issue = [&](int j, int bb) {
    const int dcol = dw + j * 16;
    float* xb = &lds[wave][bb][0][0];
    float* pb = &lds[wave][bb][1][0];
#pragma unroll
    for (int s = 0; s < 2; ++s) {
      const int r = s * 16 + r_ld;                // row 0..31
      const size_t go = base + (size_t)(m0 + r) * DMODEL + dcol + q_ld * 4;
      async_load16(x + go, xb + s * 256);         // WAVE-UNIFORM LDS base
      async_load16(p + go, pb + s * 256);
    }
  };

  issue(0, 0);
#pragma unroll
  for (int j = 0; j < 8; ++j) {
    if (j < 7) issue(j + 1, (j + 1) & 1);
    if (j == 0) {
      __builtin_amdgcn_s_waitcnt(0x0F74);         // vmcnt<=4: unit0's 4 done
    } else if (j < 7) {
      __builtin_amdgcn_s_waitcnt(0x0F75);         // vmcnt<=5: unit j's 4 done
    } else {
      __builtin_amdgcn_s_waitcnt(0x0F71);         // vmcnt<=1: unit7's 4 done
    }
    const float* xb = &lds[wave][j & 1][0][0];
    const float* pb = &lds[wave][j & 1][1][0];
    bf16x8 o;
#pragma unroll
    for (int i = 0; i < 8; ++i) {
      const int idx = (mc * 8 + i) * 16 + d_l;    // 4-way banked (1.58x, acceptable)
      o[i] = (__bf16)(xb[idx] + addf * pb[idx]);
    }
    const int dcol = dw + j * 16;
    // Store: lanes (d_l, mc) -> 16 d-rows x 64 B contiguous each.
    *(bf16x8*)(g_yt + base + (size_t)(dcol + d_l) * KLEN + (m0 + mc * 8)) = o;
  }
}

// ---------------- GEMM: out[b][l][d] = sum_m FT[l][m] * yt[b][d][m] ----------------
#define BM 128
#define BN 128
#define BK 64

__global__ __launch_bounds__(256) void gemm_kernel(float* __restrict__ out) {
  // grid: (DMODEL/BN, QLEN/BM, BATCH); 4 waves; wave tile 64x64 (4x4 of 16x16x32 MFMA)
  __shared__ __align__(16) __bf16 As[BM * BK];   // [l'][k'] chunk-swizzled, 16 KB
  __shared__ __align__(16) __bf16 Bs[BN * BK];   // [d'][k'] chunk-swizzled, 16 KB
  const int bn = blockIdx.x, bm = blockIdx.y, b = blockIdx.z;
  const int l0 = bm * BM, d0 = bn * BN;
  const int tid  = threadIdx.x;
  const int lane = tid & 63;
  const int wave = tid >> 6;
  const int wr = wave >> 1, wc = wave & 1;
  const int col = lane & 15, quad = lane >> 4;

  f32x4 acc[4][4] = {};

  // band: FT[l,m] nonzero only for l <= m <= l+1024 -> K-tiles [l0/64, (l0+1151)/64]
  const int t0 = l0 >> 6;
  const int t1 = (l0 + BM - 1 + FLEN - 1) >> 6;   // inclusive; 18 tiles
  const __bf16* ftp = g_ft;
  const __bf16* ytp = g_yt + (size_t)b * DMODEL * KLEN;

  for (int t = t0; t <= t1; ++t) {
    const int k0 = t * BK;
    // Stage A (FT) and B (y^T): both 128 rows x 64 k, row-major, 8x16B chunks/row.
    // XOR swizzle applied on GLOBAL side: LDS chunk (row, sc8) holds global chunk
    // (row, sc8 ^ (row&7)), since global_load_lds writes lane i at base + i*16.
#pragma unroll
    for (int s = 0; s < 4; ++s) {
      const int cb  = wave * 256 + s * 64;
      const int lc  = cb + lane;
      const int row = lc >> 3;
      const int gc8 = (lc & 7) ^ (row & 7);
      async_load16(ftp + (size_t)(l0 + row) * KLEN + k0 + gc8 * 8, As + cb * 8);
    }
#pragma unroll
    for (int s = 0; s < 4; ++s) {
      const int cb  = wave * 256 + s * 64;
      const int lc  = cb + lane;
      const int row = lc >> 3;
      const int gc8 = (lc & 7) ^ (row & 7);
      async_load16(ytp + (size_t)(d0 + row) * KLEN + k0 + gc8 * 8, Bs + cb * 8);
    }
    __syncthreads();   // drains vmcnt -> staged data visible

#pragma unroll
    for (int kk = 0; kk < 2; ++kk) {
      bf16x8 af[4], bq[4];
      const int c8 = kk * 4 + quad;
#pragma unroll
      for (int ti = 0; ti < 4; ++ti) {
        const int r = wr * 64 + ti * 16 + col;            // A row (l), frag m = lane&15
        af[ti] = *(const bf16x8*)(As + (size_t)((r << 3) + (c8 ^ (r & 7))) * 8);
      }
#pragma unroll
      for (int tj = 0; tj < 4; ++tj) {
        const int r = wc * 64 + tj * 16 + col;            // B row (d), frag n = lane&15
        bq[tj] = *(const bf16x8*)(Bs + (size_t)((r << 3) + (c8 ^ (r & 7))) * 8);
      }
#pragma unroll
      for (int ti = 0; ti < 4; ++ti)
#pragma unroll
        for (int tj = 0; tj < 4; ++tj)
          acc[ti][tj] = __builtin_amdgcn_mfma_f32_16x16x32_bf16(af[ti], bq[tj], acc[ti][tj], 0, 0, 0);
    }
    __syncthreads();   // protect LDS from next iteration's staging
  }

  // Epilogue: C/D layout col = lane&15, row = quad*4 + reg  [m89/m91 verified]
#pragma unroll
  for (int ti = 0; ti < 4; ++ti) {
    const int l = l0 + wr * 64 + ti * 16 + quad * 4;
#pragma unroll
    for (int tj = 0; tj < 4; ++tj) {
      const int d = d0 + wc * 64 + tj * 16 + col;
      float* op = out + (size_t)b * QLEN * DMODEL + (size_t)l * DMODEL + d;
#pragma unroll
      for (int r2 = 0; r2 < 4; ++r2) op[(size_t)r2 * DMODEL] = acc[ti][tj][r2];
    }
  }
}

extern "C" void kernel_launch(void* const* d_in, const int* in_sizes, int n_in,
                              void* d_out, int out_size, void* d_ws, size_t ws_size,
                              hipStream_t stream) {
  const float* x   = (const float*)d_in[0];
  const float* p   = (const float*)d_in[1];
  const int* addp  = (const int*)d_in[3];   // add_position (qlen fixed at 1024 by shapes)
  float* out = (float*)d_out;

  gen_ft_kernel<<<dim3((QLEN * KLEN / 8) / 256), dim3(256), 0, stream>>>();
  gen_yt_kernel<<<dim3(1024), dim3(256), 0, stream>>>(x, p, addp);
  gemm_kernel<<<dim3(DMODEL / BN, QLEN / BM, BATCH), dim3(256), 0, stream>>>(out);
}

// Round 7
// 209.863 us; speedup vs baseline: 1.0247x; 1.0247x over previous
//
#include <hip/hip_runtime.h>
#include <hip/hip_bf16.h>
#include <cstdint>

#define QLEN   1024
#define KLEN   2048
#define DMODEL 2048
#define BATCH  4
#define FLEN   (KLEN - QLEN + 1)   // 1025

typedef __bf16 bf16x8 __attribute__((ext_vector_type(8)));
typedef __bf16 bf16x4 __attribute__((ext_vector_type(4)));
typedef float  f32x4  __attribute__((ext_vector_type(4)));

// Static device scratch.
__device__ __bf16 g_ft[(size_t)QLEN * KLEN];           // FT, scale baked, bf16 (4 MB)
__device__ __bf16 g_yt[(size_t)BATCH * DMODEL * KLEN]; // y^T = (x+p)^T per batch (33.5 MB)

typedef __attribute__((address_space(1))) void gvoid;
typedef __attribute__((address_space(3))) void svoid;

__device__ __forceinline__ void async_load16(const void* g, void* lds) {
  gvoid* gp = (gvoid*)(uintptr_t)g;
  svoid* sp = (svoid*)(uint32_t)(uintptr_t)lds;   // flat LDS addr low 32 bits == LDS offset
  __builtin_amdgcn_global_load_lds(gp, sp, 16, 0, 0);
}

// ---------------- FT generation ----------------
// FT[l,m] = cos(2*pi*((l*(m-l)) % 1025)/1025) / sqrt(1025*2048) inside band l<=m<=l+1024.
__global__ void gen_ft_kernel() {
  const int u  = blockIdx.x * 256 + threadIdx.x;  // over QLEN*KLEN/8
  const int l  = u >> 8;                          // KLEN/8 = 256 chunks per row
  const int m0 = (u & 255) * 8;
  const int j0 = m0 - l;
  bf16x8 o = {};
  if (j0 + 7 >= 0 && j0 < FLEN) {
    const float w     = 6.283185307179586f / (float)FLEN;
    const float scale = 1.0f / sqrtf((float)FLEN * (float)KLEN);
#pragma unroll
    for (int i = 0; i < 8; ++i) {
      const int j = j0 + i;
      float v = 0.0f;
      if (j >= 0 && j < FLEN) {
        const int r = (l * j) % FLEN;             // exact: l*j < 2^20, magic-mul mod
        v = cosf((float)r * w) * scale;
      }
      o[i] = (__bf16)v;
    }
  }
  *(bf16x8*)(g_ft + (size_t)u * 8) = o;
}

// ---------------- y^T generation (add + cast + transpose) ----------------
// yt[b][d][m] = bf16(x[b][m][d] + addf*p[b][m][d])
//
// Round-7: block-persistent pipelined tiles. Block owns 64d x 512m; loops 8
// tiles of 64m x 64d with DOUBLE-BUFFERED global_load_lds staging. Reads are
// 256 B/row, stores 128 B/d-row (full lines — fixes round-6's 64 B-granule
// over-fetch: FETCH 91 MB, WRITE 51 MB). The tile-t+1 prefetch stays in
// flight across RAW s_barriers with manual s_waitcnt vmcnt(<=10) — never the
// vmcnt(0) drain __syncthreads would force (the m97-structure stall).
// Wave-uniform XOR chunk-swizzle keyed on (row>>3) makes the transposed LDS
// reads exactly 2-way banked (free, m136); legal with global_load_lds's
// lane-order placement because each stage instr's 4 rows share row>>3.
__global__ __launch_bounds__(256) void gen_yt_kernel(const float* __restrict__ x,
                                                     const float* __restrict__ p,
                                                     const int* __restrict__ addp) {
  __shared__ __align__(16) float xt[2][64 * 64];  // 2 x 16 KB
  __shared__ __align__(16) float pt[2][64 * 64];  // 2 x 16 KB  (64 KB total)
  const int tid  = threadIdx.x;
  const int lane = tid & 63;
  const int wave = tid >> 6;
  const float addf = (*addp) ? 1.0f : 0.0f;
  const int b      = blockIdx.z;
  const int d0     = blockIdx.y * 64;
  const int m_base = blockIdx.x * 512;
  const size_t base = (size_t)b * KLEN * DMODEL;

  const int lrow = lane >> 4;                     // stage: row within 4-row sweep
  const int lchk = lane & 15;                     // stage: 16B chunk within row

  // Stage tile t (64m x 64d fp32, x and p) into buffer bb. 8 instrs/wave.
  // LDS[row][chunk c] holds global chunk c ^ K(row), K = ((row>>3)&7)<<1.
  auto issue = [&](int t, int bb) {
    const int m0 = m_base + t * 64;
#pragma unroll
    for (int s = 0; s < 4; ++s) {
      const int r0 = wave * 16 + s * 4;           // rows r0..r0+3 (r0%4==0, same r>>3)
      const int K  = ((r0 >> 3) & 7) << 1;        // wave-uniform swizzle key
      const int gc = lchk ^ K;
      const size_t go = base + (size_t)(m0 + r0 + lrow) * DMODEL + d0 + gc * 4;
      async_load16(x + go, &xt[bb][r0 * 64]);     // wave-uniform LDS base (m104)
      async_load16(p + go, &pt[bb][r0 * 64]);
    }
  };

  // Consume tile t from buffer bb: transpose + add + cvt + 128 B/d-row stores.
  auto consume = [&](int t, int bb) {
    const int m0 = m_base + t * 64;
#pragma unroll
    for (int s = 0; s < 2; ++s) {
      const int u  = tid + 256 * s;
      const int d  = u >> 3;                      // 0..63
      const int mc = u & 7;                       // 0..7
      bf16x8 o;
#pragma unroll
      for (int i = 0; i < 8; ++i) {
        const int m   = mc * 8 + i;               // m>>3 == mc
        const int idx = m * 64 + ((d >> 2) ^ (mc << 1)) * 4 + (d & 3);  // 2-way banked
        o[i] = (__bf16)(xt[bb][idx] + addf * pt[bb][idx]);
      }
      // 8 consecutive lanes (mc 0..7, same d) -> 128 B contiguous per d-row.
      *(bf16x8*)(g_yt + base + (size_t)(d0 + d) * KLEN + (m0 + mc * 8)) = o;
    }
  };

  issue(0, 0);
#pragma unroll
  for (int t = 0; t < 8; ++t) {
    asm volatile("s_barrier" ::: "memory");       // all waves done reading buf (t+1)&1
    if (t < 7) issue(t + 1, (t + 1) & 1);
    // vmcnt: in-order retire (m135). Own queue: [stage_t(8), stores(2), stage_t+1(8)].
    if (t == 0)      __builtin_amdgcn_s_waitcnt(0x0F78);  // vmcnt<=8  (no stores yet)
    else if (t < 7)  __builtin_amdgcn_s_waitcnt(0x0F7A);  // vmcnt<=10
    else             __builtin_amdgcn_s_waitcnt(0x0F72);  // vmcnt<=2  (no stage_t+1)
    asm volatile("s_barrier" ::: "memory");       // all waves' stage_t landed
    consume(t, t & 1);
  }
}

// ---------------- GEMM: out[b][l][d] = sum_m FT[l][m] * yt[b][d][m] ----------------
#define BM 128
#define BN 128
#define BK 64

__global__ __launch_bounds__(256) void gemm_kernel(float* __restrict__ out) {
  // grid: (DMODEL/BN, QLEN/BM, BATCH); 4 waves; wave tile 64x64 (4x4 of 16x16x32 MFMA)
  __shared__ __align__(16) __bf16 As[BM * BK];   // [l'][k'] chunk-swizzled, 16 KB
  __shared__ __align__(16) __bf16 Bs[BN * BK];   // [d'][k'] chunk-swizzled, 16 KB
  const int bn = blockIdx.x, bm = blockIdx.y, b = blockIdx.z;
  const int l0 = bm * BM, d0 = bn * BN;
  const int tid  = threadIdx.x;
  const int lane = tid & 63;
  const int wave = tid >> 6;
  const int wr = wave >> 1, wc = wave & 1;
  const int col = lane & 15, quad = lane >> 4;

  f32x4 acc[4][4] = {};

  // band: FT[l,m] nonzero only for l <= m <= l+1024 -> K-tiles [l0/64, (l0+1151)/64]
  const int t0 = l0 >> 6;
  const int t1 = (l0 + BM - 1 + FLEN - 1) >> 6;   // inclusive; 18 tiles
  const __bf16* ftp = g_ft;
  const __bf16* ytp = g_yt + (size_t)b * DMODEL * KLEN;

  for (int t = t0; t <= t1; ++t) {
    const int k0 = t * BK;
    // Stage A (FT) and B (y^T): both 128 rows x 64 k, row-major, 8x16B chunks/row.
    // XOR swizzle applied on GLOBAL side: LDS chunk (row, sc8) holds global chunk
    // (row, sc8 ^ (row&7)), since global_load_lds writes lane i at base + i*16.
#pragma unroll
    for (int s = 0; s < 4; ++s) {
      const int cb  = wave * 256 + s * 64;
      const int lc  = cb + lane;
      const int row = lc >> 3;
      const int gc8 = (lc & 7) ^ (row & 7);
      async_load16(ftp + (size_t)(l0 + row) * KLEN + k0 + gc8 * 8, As + cb * 8);
    }
#pragma unroll
    for (int s = 0; s < 4; ++s) {
      const int cb  = wave * 256 + s * 64;
      const int lc  = cb + lane;
      const int row = lc >> 3;
      const int gc8 = (lc & 7) ^ (row & 7);
      async_load16(ytp + (size_t)(d0 + row) * KLEN + k0 + gc8 * 8, Bs + cb * 8);
    }
    __syncthreads();   // drains vmcnt -> staged data visible

#pragma unroll
    for (int kk = 0; kk < 2; ++kk) {
      bf16x8 af[4], bq[4];
      const int c8 = kk * 4 + quad;
#pragma unroll
      for (int ti = 0; ti < 4; ++ti) {
        const int r = wr * 64 + ti * 16 + col;            // A row (l), frag m = lane&15
        af[ti] = *(const bf16x8*)(As + (size_t)((r << 3) + (c8 ^ (r & 7))) * 8);
      }
#pragma unroll
      for (int tj = 0; tj < 4; ++tj) {
        const int r = wc * 64 + tj * 16 + col;            // B row (d), frag n = lane&15
        bq[tj] = *(const bf16x8*)(Bs + (size_t)((r << 3) + (c8 ^ (r & 7))) * 8);
      }
#pragma unroll
      for (int ti = 0; ti < 4; ++ti)
#pragma unroll
        for (int tj = 0; tj < 4; ++tj)
          acc[ti][tj] = __builtin_amdgcn_mfma_f32_16x16x32_bf16(af[ti], bq[tj], acc[ti][tj], 0, 0, 0);
    }
    __syncthreads();   // protect LDS from next iteration's staging
  }

  // Epilogue: C/D layout col = lane&15, row = quad*4 + reg  [m89/m91 verified]
#pragma unroll
  for (int ti = 0; ti < 4; ++ti) {
    const int l = l0 + wr * 64 + ti * 16 + quad * 4;
#pragma unroll
    for (int tj = 0; tj < 4; ++tj) {
      const int d = d0 + wc * 64 + tj * 16 + col;
      float* op = out + (size_t)b * QLEN * DMODEL + (size_t)l * DMODEL + d;
#pragma unroll
      for (int r2 = 0; r2 < 4; ++r2) op[(size_t)r2 * DMODEL] = acc[ti][tj][r2];
    }
  }
}

extern "C" void kernel_launch(void* const* d_in, const int* in_sizes, int n_in,
                              void* d_out, int out_size, void* d_ws, size_t ws_size,
                              hipStream_t stream) {
  const float* x   = (const float*)d_in[0];
  const float* p   = (const float*)d_in[1];
  const int* addp  = (const int*)d_in[3];   // add_position (qlen fixed at 1024 by shapes)
  float* out = (float*)d_out;

  gen_ft_kernel<<<dim3((QLEN * KLEN / 8) / 256), dim3(256), 0, stream>>>();
  gen_yt_kernel<<<dim3(4, 32, BATCH), dim3(256), 0, stream>>>(x, p, addp);
  gemm_kernel<<<dim3(DMODEL / BN, QLEN / BM, BATCH), dim3(256), 0, stream>>>(out);
}